// Round 5
// baseline (1320.673 us; speedup 1.0000x reference)
//
#include <hip/hip_runtime.h>
#include <cstdint>
#include <math.h>

#define NP 2048
#define NH 1024
#define NBATCH 32
#define ND 512
#define SD (NBATCH*ND)   // 16384: seq-row stride (floats) of premises/hypotheses [L,B,D]

typedef _Float16 f16;
typedef __attribute__((ext_vector_type(4))) _Float16 f16x4;
typedef __attribute__((ext_vector_type(8))) _Float16 f16x8;
typedef __attribute__((ext_vector_type(4))) float f32x4;

// LDS tile layout: [row][64 halves], 8-half groups XOR-swizzled by row&7.
__device__ __forceinline__ int swz_idx(int row, int g) {
    return (row << 6) + (((g ^ (row & 7)) << 3));
}

// load 8 contiguous scores as float, for either storage type
__device__ __forceinline__ void load8f(const f16* p, float* o) {
    f16x8 v = *(const f16x8*)p;
#pragma unroll
    for (int j = 0; j < 8; ++j) o[j] = (float)v[j];
}
__device__ __forceinline__ void load8f(const float* p, float* o) {
    float4 a = *(const float4*)p;
    float4 b = *(const float4*)(p + 4);
    o[0]=a.x; o[1]=a.y; o[2]=a.z; o[3]=a.w; o[4]=b.x; o[5]=b.y; o[6]=b.z; o[7]=b.w;
}

// ---------------- K1: scores[b][p][h] = sum_d P[p,b,d]*H[h,b,d] ----------------------
template<typename ST>
__global__ __launch_bounds__(512) void k1_scores(const float* __restrict__ P,
                                                 const float* __restrict__ H,
                                                 ST* __restrict__ S) {
    __shared__ f16 As[128 * 64];   // [p-row][d-k]
    __shared__ f16 Bs[256 * 64];   // [h-row][d-k]
    const int b    = blockIdx.z;
    const int prow = blockIdx.y * 128;
    const int hcol = blockIdx.x * 256;
    const int tid  = threadIdx.x;
    const int lane = tid & 63, wid = tid >> 6;
    const int wr = wid >> 2, wc = wid & 3;     // 2 x 4 waves, wave tile 64x64
    const int l15 = lane & 15, lhi = lane >> 4;

    f32x4 acc[4][4] = {};

    for (int kt = 0; kt < 8; ++kt) {
        const int k0 = kt * 64;
        __syncthreads();
#pragma unroll
        for (int i = 0; i < 4; ++i) {          // stage A: 128 p-rows x 64 d
            int s4 = tid + 512 * i;
            int row = s4 >> 4;
            int c4 = (s4 & 15) << 2;
            float4 v = *(const float4*)(P + (size_t)(prow + row) * SD + b * ND + k0 + c4);
            f16x4 h4 = {(f16)v.x, (f16)v.y, (f16)v.z, (f16)v.w};
            *(f16x4*)&As[swz_idx(row, c4 >> 3) + (c4 & 7)] = h4;
        }
#pragma unroll
        for (int i = 0; i < 8; ++i) {          // stage B: 256 h-rows x 64 d
            int s4 = tid + 512 * i;
            int row = s4 >> 4;
            int c4 = (s4 & 15) << 2;
            float4 v = *(const float4*)(H + (size_t)(hcol + row) * SD + b * ND + k0 + c4);
            f16x4 h4 = {(f16)v.x, (f16)v.y, (f16)v.z, (f16)v.w};
            *(f16x4*)&Bs[swz_idx(row, c4 >> 3) + (c4 & 7)] = h4;
        }
        __syncthreads();
#pragma unroll
        for (int ks = 0; ks < 2; ++ks) {
            f16x8 a[4], bb[4];
#pragma unroll
            for (int m = 0; m < 4; ++m)
                a[m] = *(const f16x8*)&As[swz_idx(wr * 64 + m * 16 + l15, ks * 4 + lhi)];
#pragma unroll
            for (int n = 0; n < 4; ++n)
                bb[n] = *(const f16x8*)&Bs[swz_idx(wc * 64 + n * 16 + l15, ks * 4 + lhi)];
#pragma unroll
            for (int m = 0; m < 4; ++m)
#pragma unroll
                for (int n = 0; n < 4; ++n)
                    acc[m][n] = __builtin_amdgcn_mfma_f32_16x16x32_f16(a[m], bb[n], acc[m][n], 0, 0, 0);
        }
    }
    const size_t sb = (size_t)b * NP * NH;
#pragma unroll
    for (int m = 0; m < 4; ++m)
#pragma unroll
        for (int n = 0; n < 4; ++n) {
            int col = hcol + wc * 64 + n * 16 + l15;
#pragma unroll
            for (int r = 0; r < 4; ++r) {
                int row = prow + wr * 64 + m * 16 + lhi * 4 + r;
                S[sb + (size_t)row * NH + col] = (ST)acc[m][n][r];
            }
        }
}

// ---------------- K2: per (b,p) row masked max / inv-sum over Nh ---------------------
template<typename ST>
__global__ __launch_bounds__(256) void k2_rowstats(const ST* __restrict__ S,
                                                   const int* __restrict__ pmask,
                                                   float2* __restrict__ rstats) {
    const int rowid = blockIdx.x * 4 + (threadIdx.x >> 6);   // b*2048+p
    const int lane  = threadIdx.x & 63;
    const int b     = rowid >> 11;
    const ST* row   = S + (size_t)rowid * NH + lane * 16;
    float s[16];
    load8f(row, s);
    load8f(row + 8, s + 8);
    int mk[16];
    {
        const int* mp = pmask + b * NH + lane * 16;
#pragma unroll
        for (int j = 0; j < 16; ++j) mk[j] = mp[j];
    }
    float m = -INFINITY;
#pragma unroll
    for (int j = 0; j < 16; ++j) if (mk[j]) m = fmaxf(m, s[j]);
#pragma unroll
    for (int off = 32; off; off >>= 1) m = fmaxf(m, __shfl_xor(m, off));
    float sum = 0.0f;
#pragma unroll
    for (int j = 0; j < 16; ++j) if (mk[j]) sum += __expf(s[j] - m);
#pragma unroll
    for (int off = 32; off; off >>= 1) sum += __shfl_xor(sum, off);
    if (lane == 0) rstats[rowid] = make_float2(m, sum > 0.0f ? 1.0f / sum : 0.0f);
}

// ---------------- K3a: per (b,h) partial masked online max/sum over a p-chunk --------
template<typename ST>
__global__ __launch_bounds__(256) void k3a_colpart(const ST* __restrict__ S,
                                                   const int* __restrict__ hmask,
                                                   float2* __restrict__ cpart) {
    const int b  = blockIdx.z;
    const int h  = blockIdx.x * 256 + threadIdx.x;
    const int pc = blockIdx.y;
    const ST* base = S + (size_t)b * NP * NH + h;
    const int* hm  = hmask + b * NP;
    float m = -INFINITY, sum = 0.0f;
    const int p0 = pc * 256;
    for (int p = p0; p < p0 + 256; ++p) {
        float s = (float)base[(size_t)p * NH];
        if (hm[p]) {
            if (s <= m) sum += __expf(s - m);
            else { sum = sum * __expf(m - s) + 1.0f; m = s; }
        }
    }
    cpart[((size_t)pc * NBATCH + b) * NH + h] = make_float2(m, sum);
}

// ---------------- K3b: merge 8 partials -> cstats ------------------------------------
__global__ __launch_bounds__(256) void k3b_colmerge(const float2* __restrict__ cpart,
                                                    float2* __restrict__ cstats) {
    const int cid = blockIdx.x * 256 + threadIdx.x;  // b*NH + h
    float2 v[8];
    float M = -INFINITY;
#pragma unroll
    for (int pc = 0; pc < 8; ++pc) {
        v[pc] = cpart[(size_t)pc * (NBATCH * NH) + cid];
        M = fmaxf(M, v[pc].x);
    }
    float Ssum = 0.0f;
#pragma unroll
    for (int pc = 0; pc < 8; ++pc)
        if (v[pc].y > 0.0f) Ssum += v[pc].y * __expf(v[pc].x - M);
    cstats[cid] = make_float2(M, Ssum > 0.0f ? 1.0f / Ssum : 0.0f);
}

// ---------------- K4: new_premises = softmax_rows(S) @ H -----------------------------
template<typename ST>
__global__ __launch_bounds__(512) void k4_newp(const ST* __restrict__ S,
                                               const float* __restrict__ H,
                                               const int* __restrict__ pmask,
                                               const float2* __restrict__ rstats,
                                               float* __restrict__ out) {
    __shared__ f16 As[128 * 64];    // [p-row][h-k]  softmax weights
    __shared__ f16 Bs[256 * 64];    // [d-row][h-k]  H transposed
    __shared__ float rm[128], ri[128];
    const int b    = blockIdx.z;
    const int prow = blockIdx.y * 128;
    const int d0   = blockIdx.x * 256;
    const int tid  = threadIdx.x;
    const int lane = tid & 63, wid = tid >> 6;
    const int wr = wid >> 2, wc = wid & 3;
    const int l15 = lane & 15, lhi = lane >> 4;

    if (tid < 128) {
        float2 v = rstats[b * NP + prow + tid];
        rm[tid] = v.x; ri[tid] = v.y;
    }

    f32x4 acc[4][4] = {};

    for (int kt = 0; kt < 16; ++kt) {
        const int k0 = kt * 64;
        __syncthreads();
#pragma unroll
        for (int i = 0; i < 2; ++i) {          // A: 128 p-rows x 64 h, fused exp
            int s8 = tid + 512 * i;
            int row = s8 >> 3;
            int c8 = (s8 & 7) << 3;
            float sv[8];
            load8f(S + ((size_t)(b * NP) + prow + row) * NH + k0 + c8, sv);
            const int* pm = pmask + b * NH + k0 + c8;
            float mrow = rm[row], irow = ri[row];
            f16x8 w;
#pragma unroll
            for (int j = 0; j < 8; ++j) {
                float e = __expf(sv[j] - mrow) * irow;
                w[j] = pm[j] ? (f16)e : (f16)0.0f;
            }
            *(f16x8*)&As[swz_idx(row, c8 >> 3)] = w;
        }
#pragma unroll
        for (int i = 0; i < 4; ++i) {          // B: 256 d-rows x 64 h (H transposed)
            int slot = tid + 512 * i;
            int d = slot & 255;
            int g = slot >> 8;
            f16x8 w;
#pragma unroll
            for (int j = 0; j < 8; ++j)
                w[j] = (f16)H[(size_t)(k0 + g * 8 + j) * SD + b * ND + d0 + d];
            *(f16x8*)&Bs[swz_idx(d, g)] = w;
        }
        __syncthreads();
#pragma unroll
        for (int ks = 0; ks < 2; ++ks) {
            f16x8 a[4], bb[4];
#pragma unroll
            for (int m = 0; m < 4; ++m)
                a[m] = *(const f16x8*)&As[swz_idx(wr * 64 + m * 16 + l15, ks * 4 + lhi)];
#pragma unroll
            for (int n = 0; n < 4; ++n)
                bb[n] = *(const f16x8*)&Bs[swz_idx(wc * 64 + n * 16 + l15, ks * 4 + lhi)];
#pragma unroll
            for (int m = 0; m < 4; ++m)
#pragma unroll
                for (int n = 0; n < 4; ++n)
                    acc[m][n] = __builtin_amdgcn_mfma_f32_16x16x32_f16(a[m], bb[n], acc[m][n], 0, 0, 0);
        }
    }
#pragma unroll
    for (int m = 0; m < 4; ++m)
#pragma unroll
        for (int n = 0; n < 4; ++n) {
            int col = d0 + wc * 64 + n * 16 + l15;
#pragma unroll
            for (int r = 0; r < 4; ++r) {
                int row = prow + wr * 64 + m * 16 + lhi * 4 + r;
                out[((size_t)(b * NP) + row) * ND + col] = acc[m][n][r];
            }
        }
}

// ---------------- K5: new_hypotheses = softmax_cols(S)^T @ P -------------------------
template<typename ST>
__global__ __launch_bounds__(512) void k5_newh(const ST* __restrict__ S,
                                               const float* __restrict__ P,
                                               const int* __restrict__ hmask,
                                               const float2* __restrict__ cstats,
                                               float* __restrict__ out2) {
    __shared__ f16 As[128 * 64];   // [h-row][p-k]  weights (from S transposed)
    __shared__ f16 Bs[256 * 64];   // [d-row][p-k]  P transposed
    const int b    = blockIdx.z;
    const int hrow = blockIdx.y * 128;
    const int d0   = blockIdx.x * 256;
    const int tid  = threadIdx.x;
    const int lane = tid & 63, wid = tid >> 6;
    const int wr = wid >> 2, wc = wid & 3;
    const int l15 = lane & 15, lhi = lane >> 4;

    f32x4 acc[4][4] = {};

    for (int kt = 0; kt < 32; ++kt) {
        const int k0 = kt * 64;    // p offset
        __syncthreads();
#pragma unroll
        for (int i = 0; i < 2; ++i) {          // A: 128 h-rows x 64 p (S transposed)
            int slot = tid + 512 * i;
            int hh = slot & 127;
            int g = slot >> 7;
            float2 cs = cstats[b * NH + hrow + hh];
            f16x8 w;
#pragma unroll
            for (int j = 0; j < 8; ++j) {
                int p = k0 + g * 8 + j;
                float s = (float)S[((size_t)(b * NP) + p) * NH + hrow + hh];
                float e = __expf(s - cs.x) * cs.y;
                w[j] = hmask[b * NP + p] ? (f16)e : (f16)0.0f;
            }
            *(f16x8*)&As[swz_idx(hh, g)] = w;
        }
#pragma unroll
        for (int i = 0; i < 4; ++i) {          // B: 256 d-rows x 64 p (P transposed)
            int slot = tid + 512 * i;
            int d = slot & 255;
            int g = slot >> 8;
            f16x8 w;
#pragma unroll
            for (int j = 0; j < 8; ++j)
                w[j] = (f16)P[(size_t)(k0 + g * 8 + j) * SD + b * ND + d0 + d];
            *(f16x8*)&Bs[swz_idx(d, g)] = w;
        }
        __syncthreads();
#pragma unroll
        for (int ks = 0; ks < 2; ++ks) {
            f16x8 a[4], bb[4];
#pragma unroll
            for (int m = 0; m < 4; ++m)
                a[m] = *(const f16x8*)&As[swz_idx(wr * 64 + m * 16 + l15, ks * 4 + lhi)];
#pragma unroll
            for (int n = 0; n < 4; ++n)
                bb[n] = *(const f16x8*)&Bs[swz_idx(wc * 64 + n * 16 + l15, ks * 4 + lhi)];
#pragma unroll
            for (int m = 0; m < 4; ++m)
#pragma unroll
                for (int n = 0; n < 4; ++n)
                    acc[m][n] = __builtin_amdgcn_mfma_f32_16x16x32_f16(a[m], bb[n], acc[m][n], 0, 0, 0);
        }
    }
#pragma unroll
    for (int m = 0; m < 4; ++m)
#pragma unroll
        for (int n = 0; n < 4; ++n) {
            int col = d0 + wc * 64 + n * 16 + l15;
#pragma unroll
            for (int r = 0; r < 4; ++r) {
                int row = hrow + wr * 64 + m * 16 + lhi * 4 + r;
                out2[((size_t)(b * NH) + row) * ND + col] = acc[m][n][r];
            }
        }
}

template<typename ST>
static void launch_all(const float* premises, const int* premises_mask,
                       const float* hypotheses, const int* hypotheses_mask,
                       float* out, float* out2, char* wsc, hipStream_t stream) {
    const size_t s_bytes = (size_t)NBATCH * NP * NH * sizeof(ST);
    ST*     S      = (ST*)wsc;
    float2* rstats = (float2*)(wsc + s_bytes);
    float2* cstats = (float2*)(wsc + s_bytes + 524288);
    float2* cpart  = (float2*)(wsc + s_bytes + 524288 + 262144);

    k1_scores<ST>  <<<dim3(4, 16, NBATCH), 512, 0, stream>>>(premises, hypotheses, S);
    k2_rowstats<ST><<<dim3(16384), 256, 0, stream>>>(S, premises_mask, rstats);
    k3a_colpart<ST><<<dim3(4, 8, NBATCH), 256, 0, stream>>>(S, hypotheses_mask, cpart);
    k3b_colmerge   <<<dim3(128), 256, 0, stream>>>(cpart, cstats);
    k4_newp<ST>    <<<dim3(2, 16, NBATCH), 512, 0, stream>>>(S, hypotheses, premises_mask, rstats, out);
    k5_newh<ST>    <<<dim3(2, 8, NBATCH), 512, 0, stream>>>(S, premises, hypotheses_mask, cstats, out2);
}

extern "C" void kernel_launch(void* const* d_in, const int* in_sizes, int n_in,
                              void* d_out, int out_size, void* d_ws, size_t ws_size,
                              hipStream_t stream) {
    const float* premises        = (const float*)d_in[0];
    const int*   premises_mask   = (const int*)d_in[1];
    const float* hypotheses      = (const float*)d_in[2];
    const int*   hypotheses_mask = (const int*)d_in[3];

    float* out  = (float*)d_out;
    float* out2 = out + (size_t)NBATCH * NP * ND;
    char*  wsc  = (char*)d_ws;

    // fp32 scores need 268.4MB + 2.9MB stats; f16 fallback needs 134.2MB + 2.9MB.
    const size_t need_f32 = (size_t)NBATCH * NP * NH * 4 + 4 * 1024 * 1024;
    if (ws_size >= need_f32)
        launch_all<float>(premises, premises_mask, hypotheses, hypotheses_mask, out, out2, wsc, stream);
    else
        launch_all<f16>(premises, premises_mask, hypotheses, hypotheses_mask, out, out2, wsc, stream);
}

// Round 8
// 1105.680 us; speedup vs baseline: 1.1944x; 1.1944x over previous
//
#include <hip/hip_runtime.h>
#include <cstdint>
#include <math.h>

#define NP 2048
#define NH 1024
#define NBATCH 32
#define ND 512
#define SD (NBATCH*ND)   // 16384: seq-row stride (floats) of premises/hypotheses [L,B,D]

typedef _Float16 f16;
typedef __attribute__((ext_vector_type(4))) _Float16 f16x4;
typedef __attribute__((ext_vector_type(8))) _Float16 f16x8;
typedef __attribute__((ext_vector_type(4))) float f32x4;

// LDS tile layout: [row][64 halves], 8-half groups XOR-swizzled by row&7.
__device__ __forceinline__ int swz_idx(int row, int g) {
    return (row << 6) + ((g ^ (row & 7)) << 3);
}

__device__ __forceinline__ void load8f(const f16* p, float* o) {
    f16x8 v = *(const f16x8*)p;
#pragma unroll
    for (int j = 0; j < 8; ++j) o[j] = (float)v[j];
}
__device__ __forceinline__ void load8f(const float* p, float* o) {
    float4 a = *(const float4*)p;
    float4 b = *(const float4*)(p + 4);
    o[0]=a.x; o[1]=a.y; o[2]=a.z; o[3]=a.w; o[4]=b.x; o[5]=b.y; o[6]=b.z; o[7]=b.w;
}

// ---------------- T0: transpose [L,B,D] fp32 -> [B][D][L] f16 ------------------------
template<int L>
__global__ __launch_bounds__(256) void tr_f16(const float* __restrict__ src,
                                              f16* __restrict__ dst) {
    __shared__ f16 t[64][68];               // +4 pad: write/read ~2-way max
    const int b  = blockIdx.z;
    const int l0 = blockIdx.x * 64;
    const int d0 = blockIdx.y * 64;
    const int r  = threadIdx.x >> 4;        // 0..15
    const int c  = threadIdx.x & 15;        // 0..15
#pragma unroll
    for (int i = 0; i < 4; ++i) {
        int l = r + 16 * i;
        float4 v = *(const float4*)(src + (size_t)(l0 + l) * SD + b * ND + d0 + c * 4);
        f16x4 h = {(f16)v.x, (f16)v.y, (f16)v.z, (f16)v.w};
        *(f16x4*)&t[l][c * 4] = h;          // 8B-aligned (row stride 136B = 17*8)
    }
    __syncthreads();
#pragma unroll
    for (int i = 0; i < 4; ++i) {
        int d = r + 16 * i;
        f16x4 h;
#pragma unroll
        for (int j = 0; j < 4; ++j) h[j] = t[c * 4 + j][d];
        *(f16x4*)(dst + ((size_t)b * ND + d0 + d) * L + l0 + c * 4) = h;
    }
}

// ---------------- K1: scores[b][p][h] = sum_d P[p,b,d]*H[h,b,d] ----------------------
template<typename ST>
__global__ __launch_bounds__(512) void k1_scores(const float* __restrict__ P,
                                                 const float* __restrict__ H,
                                                 ST* __restrict__ S) {
    __shared__ f16 As[128 * 64];   // [p-row][d-k]
    __shared__ f16 Bs[256 * 64];   // [h-row][d-k]
    const int b    = blockIdx.z;
    const int prow = blockIdx.y * 128;
    const int hcol = blockIdx.x * 256;
    const int tid  = threadIdx.x;
    const int lane = tid & 63, wid = tid >> 6;
    const int wr = wid >> 2, wc = wid & 3;     // 2 x 4 waves, wave tile 64x64
    const int l15 = lane & 15, lhi = lane >> 4;

    f32x4 acc[4][4] = {};

    for (int kt = 0; kt < 8; ++kt) {
        const int k0 = kt * 64;
        __syncthreads();
#pragma unroll
        for (int i = 0; i < 4; ++i) {          // stage A: 128 p-rows x 64 d
            int s4 = tid + 512 * i;
            int row = s4 >> 4;
            int c4 = (s4 & 15) << 2;
            float4 v = *(const float4*)(P + (size_t)(prow + row) * SD + b * ND + k0 + c4);
            f16x4 h4 = {(f16)v.x, (f16)v.y, (f16)v.z, (f16)v.w};
            *(f16x4*)&As[swz_idx(row, c4 >> 3) + (c4 & 7)] = h4;
        }
#pragma unroll
        for (int i = 0; i < 8; ++i) {          // stage B: 256 h-rows x 64 d
            int s4 = tid + 512 * i;
            int row = s4 >> 4;
            int c4 = (s4 & 15) << 2;
            float4 v = *(const float4*)(H + (size_t)(hcol + row) * SD + b * ND + k0 + c4);
            f16x4 h4 = {(f16)v.x, (f16)v.y, (f16)v.z, (f16)v.w};
            *(f16x4*)&Bs[swz_idx(row, c4 >> 3) + (c4 & 7)] = h4;
        }
        __syncthreads();
#pragma unroll
        for (int ks = 0; ks < 2; ++ks) {
            f16x8 a[4], bb[4];
#pragma unroll
            for (int m = 0; m < 4; ++m)
                a[m] = *(const f16x8*)&As[swz_idx(wr * 64 + m * 16 + l15, ks * 4 + lhi)];
#pragma unroll
            for (int n = 0; n < 4; ++n)
                bb[n] = *(const f16x8*)&Bs[swz_idx(wc * 64 + n * 16 + l15, ks * 4 + lhi)];
#pragma unroll
            for (int m = 0; m < 4; ++m)
#pragma unroll
                for (int n = 0; n < 4; ++n)
                    acc[m][n] = __builtin_amdgcn_mfma_f32_16x16x32_f16(a[m], bb[n], acc[m][n], 0, 0, 0);
        }
    }
    const size_t sb = (size_t)b * NP * NH;
#pragma unroll
    for (int m = 0; m < 4; ++m)
#pragma unroll
        for (int n = 0; n < 4; ++n) {
            int col = hcol + wc * 64 + n * 16 + l15;
#pragma unroll
            for (int r = 0; r < 4; ++r) {
                int row = prow + wr * 64 + m * 16 + lhi * 4 + r;
                S[sb + (size_t)row * NH + col] = (ST)acc[m][n][r];
            }
        }
}

// ---------------- K2: per (b,p) row masked max / inv-sum over Nh ---------------------
template<typename ST>
__global__ __launch_bounds__(256) void k2_rowstats(const ST* __restrict__ S,
                                                   const int* __restrict__ pmask,
                                                   float2* __restrict__ rstats) {
    const int rowid = blockIdx.x * 4 + (threadIdx.x >> 6);   // b*2048+p
    const int lane  = threadIdx.x & 63;
    const int b     = rowid >> 11;
    const ST* row   = S + (size_t)rowid * NH + lane * 16;
    float s[16];
    load8f(row, s);
    load8f(row + 8, s + 8);
    int mk[16];
    {
        const int* mp = pmask + b * NH + lane * 16;
#pragma unroll
        for (int j = 0; j < 16; ++j) mk[j] = mp[j];
    }
    float m = -INFINITY;
#pragma unroll
    for (int j = 0; j < 16; ++j) if (mk[j]) m = fmaxf(m, s[j]);
#pragma unroll
    for (int off = 32; off; off >>= 1) m = fmaxf(m, __shfl_xor(m, off));
    float sum = 0.0f;
#pragma unroll
    for (int j = 0; j < 16; ++j) if (mk[j]) sum += __expf(s[j] - m);
#pragma unroll
    for (int off = 32; off; off >>= 1) sum += __shfl_xor(sum, off);
    if (lane == 0) rstats[rowid] = make_float2(m, sum > 0.0f ? 1.0f / sum : 0.0f);
}

// ---------------- K3a: per (b,h) partial masked online max/sum over a p-chunk --------
template<typename ST>
__global__ __launch_bounds__(256) void k3a_colpart(const ST* __restrict__ S,
                                                   const int* __restrict__ hmask,
                                                   float2* __restrict__ cpart) {
    const int b  = blockIdx.z;
    const int h  = blockIdx.x * 256 + threadIdx.x;
    const int pc = blockIdx.y;
    const ST* base = S + (size_t)b * NP * NH + h;
    const int* hm  = hmask + b * NP;
    float m = -INFINITY, sum = 0.0f;
    const int p0 = pc * 256;
    for (int p = p0; p < p0 + 256; ++p) {
        float s = (float)base[(size_t)p * NH];
        if (hm[p]) {
            if (s <= m) sum += __expf(s - m);
            else { sum = sum * __expf(m - s) + 1.0f; m = s; }
        }
    }
    cpart[((size_t)pc * NBATCH + b) * NH + h] = make_float2(m, sum);
}

// ---------------- K3b: merge 8 partials -> cstats ------------------------------------
__global__ __launch_bounds__(256) void k3b_colmerge(const float2* __restrict__ cpart,
                                                    float2* __restrict__ cstats) {
    const int cid = blockIdx.x * 256 + threadIdx.x;  // b*NH + h
    float2 v[8];
    float M = -INFINITY;
#pragma unroll
    for (int pc = 0; pc < 8; ++pc) {
        v[pc] = cpart[(size_t)pc * (NBATCH * NH) + cid];
        M = fmaxf(M, v[pc].x);
    }
    float Ssum = 0.0f;
#pragma unroll
    for (int pc = 0; pc < 8; ++pc)
        if (v[pc].y > 0.0f) Ssum += v[pc].y * __expf(v[pc].x - M);
    cstats[cid] = make_float2(M, Ssum > 0.0f ? 1.0f / Ssum : 0.0f);
}

// ---------------- K4 v2: new_premises = softmax_rows(S) @ H --------------------------
// Block: 64 p-rows x full D=512. 8 waves, wave d-tile 64. S read exactly once.
__global__ __launch_bounds__(512) void k4_v2(const float* __restrict__ S,
                                             const f16* __restrict__ Ht,
                                             const int* __restrict__ pmask,
                                             const float2* __restrict__ rstats,
                                             float* __restrict__ out) {
    __shared__ f16 As[64 * 64];    // [p][h-k]  softmax weights
    __shared__ f16 Bs[512 * 64];   // [d][h-k]  from Ht (already transposed)
    __shared__ float rm[64], ri[64];
    const int b    = blockIdx.z;
    const int prow = blockIdx.y * 64;
    const int tid  = threadIdx.x;
    const int lane = tid & 63, wid = tid >> 6;
    const int l15 = lane & 15, lhi = lane >> 4;

    if (tid < 64) {
        float2 v = rstats[b * NP + prow + tid];
        rm[tid] = v.x; ri[tid] = v.y;
    }
    const int arow = tid >> 3;          // 0..63
    const int ac8  = (tid & 7) << 3;    // 0..56

    f32x4 acc[4][4] = {};

    for (int kt = 0; kt < 16; ++kt) {
        const int k0 = kt * 64;
        __syncthreads();
        // A: 64 p x 64 h, fused exp (one f16x8 slot per thread)
        {
            float sv[8];
            load8f(S + ((size_t)(b * NP) + prow + arow) * NH + k0 + ac8, sv);
            const int* pm = pmask + b * NH + k0 + ac8;
            float mrow = rm[arow], irow = ri[arow];
            f16x8 w;
#pragma unroll
            for (int j = 0; j < 8; ++j) {
                float e = __expf(sv[j] - mrow) * irow;
                w[j] = pm[j] ? (f16)e : (f16)0.0f;
            }
            *(f16x8*)&As[swz_idx(arow, ac8 >> 3)] = w;
        }
        // B: 512 d x 64 h, vectorized f16x8 copy from Ht
#pragma unroll
        for (int i = 0; i < 8; ++i) {
            int slot = tid + 512 * i;
            int d = slot >> 3, g = slot & 7;
            f16x8 w = *(const f16x8*)(Ht + ((size_t)b * ND + d) * NH + k0 + g * 8);
            *(f16x8*)&Bs[swz_idx(d, g)] = w;
        }
        __syncthreads();
#pragma unroll
        for (int ks = 0; ks < 2; ++ks) {
            f16x8 a[4], bb[4];
#pragma unroll
            for (int m = 0; m < 4; ++m)
                a[m] = *(const f16x8*)&As[swz_idx(m * 16 + l15, ks * 4 + lhi)];
#pragma unroll
            for (int n = 0; n < 4; ++n)
                bb[n] = *(const f16x8*)&Bs[swz_idx(wid * 64 + n * 16 + l15, ks * 4 + lhi)];
#pragma unroll
            for (int m = 0; m < 4; ++m)
#pragma unroll
                for (int n = 0; n < 4; ++n)
                    acc[m][n] = __builtin_amdgcn_mfma_f32_16x16x32_f16(a[m], bb[n], acc[m][n], 0, 0, 0);
        }
    }
#pragma unroll
    for (int m = 0; m < 4; ++m)
#pragma unroll
        for (int n = 0; n < 4; ++n) {
            int col = wid * 64 + n * 16 + l15;
#pragma unroll
            for (int r = 0; r < 4; ++r) {
                int row = prow + m * 16 + lhi * 4 + r;
                out[((size_t)(b * NP) + row) * ND + col] = acc[m][n][r];
            }
        }
}

// ---------------- K5 v2: new_hypotheses = softmax_cols(S)^T @ P ----------------------
// Block: 64 h-rows x full D=512. 8 waves, wave d-tile 64. S read exactly once.
__global__ __launch_bounds__(512) void k5_v2(const float* __restrict__ S,
                                             const f16* __restrict__ Pt,
                                             const int* __restrict__ hmask,
                                             const float2* __restrict__ cstats,
                                             float* __restrict__ out2) {
    __shared__ f16 As[64 * 64];    // [h][p-k]  weights (from S transposed read)
    __shared__ f16 Bs[512 * 64];   // [d][p-k]  from Pt (already transposed)
    const int b    = blockIdx.z;
    const int hrow = blockIdx.y * 64;
    const int tid  = threadIdx.x;
    const int lane = tid & 63, wid = tid >> 6;
    const int l15 = lane & 15, lhi = lane >> 4;

    const int hh = lane;                                  // A-stage row
    const float2 cs = cstats[b * NH + hrow + hh];         // hoisted out of K-loop
    const int* hm = hmask + b * NP;

    f32x4 acc[4][4] = {};

    for (int kt = 0; kt < 32; ++kt) {
        const int k0 = kt * 64;
        __syncthreads();
        // A: 64 h x 64 p; wave `wid` covers p-group wid*8..+8; h-coalesced 4B loads
        {
            f16x8 w;
#pragma unroll
            for (int j = 0; j < 8; ++j) {
                int p = k0 + wid * 8 + j;
                float s = S[((size_t)(b * NP) + p) * NH + hrow + hh];
                float e = __expf(s - cs.x) * cs.y;
                w[j] = hm[p] ? (f16)e : (f16)0.0f;
            }
            *(f16x8*)&As[swz_idx(hh, wid)] = w;
        }
        // B: 512 d x 64 p, vectorized f16x8 copy from Pt
#pragma unroll
        for (int i = 0; i < 8; ++i) {
            int slot = tid + 512 * i;
            int d = slot >> 3, g = slot & 7;
            f16x8 w = *(const f16x8*)(Pt + ((size_t)b * ND + d) * NP + k0 + g * 8);
            *(f16x8*)&Bs[swz_idx(d, g)] = w;
        }
        __syncthreads();
#pragma unroll
        for (int ks = 0; ks < 2; ++ks) {
            f16x8 a[4], bb[4];
#pragma unroll
            for (int m = 0; m < 4; ++m)
                a[m] = *(const f16x8*)&As[swz_idx(m * 16 + l15, ks * 4 + lhi)];
#pragma unroll
            for (int n = 0; n < 4; ++n)
                bb[n] = *(const f16x8*)&Bs[swz_idx(wid * 64 + n * 16 + l15, ks * 4 + lhi)];
#pragma unroll
            for (int m = 0; m < 4; ++m)
#pragma unroll
                for (int n = 0; n < 4; ++n)
                    acc[m][n] = __builtin_amdgcn_mfma_f32_16x16x32_f16(a[m], bb[n], acc[m][n], 0, 0, 0);
        }
    }
#pragma unroll
    for (int m = 0; m < 4; ++m)
#pragma unroll
        for (int n = 0; n < 4; ++n) {
            int col = wid * 64 + n * 16 + l15;
#pragma unroll
            for (int r = 0; r < 4; ++r) {
                int row = hrow + m * 16 + lhi * 4 + r;
                out2[((size_t)(b * NH) + row) * ND + col] = acc[m][n][r];
            }
        }
}

// ---------------- legacy K4/K5 (fallback tiers) --------------------------------------
template<typename ST>
__global__ __launch_bounds__(512) void k4_newp(const ST* __restrict__ S,
                                               const float* __restrict__ H,
                                               const int* __restrict__ pmask,
                                               const float2* __restrict__ rstats,
                                               float* __restrict__ out) {
    __shared__ f16 As[128 * 64];
    __shared__ f16 Bs[256 * 64];
    __shared__ float rm[128], ri[128];
    const int b    = blockIdx.z;
    const int prow = blockIdx.y * 128;
    const int d0   = blockIdx.x * 256;
    const int tid  = threadIdx.x;
    const int lane = tid & 63, wid = tid >> 6;
    const int wr = wid >> 2, wc = wid & 3;
    const int l15 = lane & 15, lhi = lane >> 4;

    if (tid < 128) {
        float2 v = rstats[b * NP + prow + tid];
        rm[tid] = v.x; ri[tid] = v.y;
    }
    f32x4 acc[4][4] = {};
    for (int kt = 0; kt < 16; ++kt) {
        const int k0 = kt * 64;
        __syncthreads();
#pragma unroll
        for (int i = 0; i < 2; ++i) {
            int s8 = tid + 512 * i;
            int row = s8 >> 3;
            int c8 = (s8 & 7) << 3;
            float sv[8];
            load8f(S + ((size_t)(b * NP) + prow + row) * NH + k0 + c8, sv);
            const int* pm = pmask + b * NH + k0 + c8;
            float mrow = rm[row], irow = ri[row];
            f16x8 w;
#pragma unroll
            for (int j = 0; j < 8; ++j) {
                float e = __expf(sv[j] - mrow) * irow;
                w[j] = pm[j] ? (f16)e : (f16)0.0f;
            }
            *(f16x8*)&As[swz_idx(row, c8 >> 3)] = w;
        }
#pragma unroll
        for (int i = 0; i < 4; ++i) {
            int slot = tid + 512 * i;
            int d = slot & 255;
            int g = slot >> 8;
            f16x8 w;
#pragma unroll
            for (int j = 0; j < 8; ++j)
                w[j] = (f16)H[(size_t)(k0 + g * 8 + j) * SD + b * ND + d0 + d];
            *(f16x8*)&Bs[swz_idx(d, g)] = w;
        }
        __syncthreads();
#pragma unroll
        for (int ks = 0; ks < 2; ++ks) {
            f16x8 a[4], bb[4];
#pragma unroll
            for (int m = 0; m < 4; ++m)
                a[m] = *(const f16x8*)&As[swz_idx(wr * 64 + m * 16 + l15, ks * 4 + lhi)];
#pragma unroll
            for (int n = 0; n < 4; ++n)
                bb[n] = *(const f16x8*)&Bs[swz_idx(wc * 64 + n * 16 + l15, ks * 4 + lhi)];
#pragma unroll
            for (int m = 0; m < 4; ++m)
#pragma unroll
                for (int n = 0; n < 4; ++n)
                    acc[m][n] = __builtin_amdgcn_mfma_f32_16x16x32_f16(a[m], bb[n], acc[m][n], 0, 0, 0);
        }
    }
#pragma unroll
    for (int m = 0; m < 4; ++m)
#pragma unroll
        for (int n = 0; n < 4; ++n) {
            int col = d0 + wc * 64 + n * 16 + l15;
#pragma unroll
            for (int r = 0; r < 4; ++r) {
                int row = prow + wr * 64 + m * 16 + lhi * 4 + r;
                out[((size_t)(b * NP) + row) * ND + col] = acc[m][n][r];
            }
        }
}

template<typename ST>
__global__ __launch_bounds__(512) void k5_newh(const ST* __restrict__ S,
                                               const float* __restrict__ P,
                                               const int* __restrict__ hmask,
                                               const float2* __restrict__ cstats,
                                               float* __restrict__ out2) {
    __shared__ f16 As[128 * 64];
    __shared__ f16 Bs[256 * 64];
    const int b    = blockIdx.z;
    const int hrow = blockIdx.y * 128;
    const int d0   = blockIdx.x * 256;
    const int tid  = threadIdx.x;
    const int lane = tid & 63, wid = tid >> 6;
    const int wr = wid >> 2, wc = wid & 3;
    const int l15 = lane & 15, lhi = lane >> 4;

    f32x4 acc[4][4] = {};
    for (int kt = 0; kt < 32; ++kt) {
        const int k0 = kt * 64;
        __syncthreads();
#pragma unroll
        for (int i = 0; i < 2; ++i) {
            int slot = tid + 512 * i;
            int hh = slot & 127;
            int g = slot >> 7;
            float2 cs = cstats[b * NH + hrow + hh];
            f16x8 w;
#pragma unroll
            for (int j = 0; j < 8; ++j) {
                int p = k0 + g * 8 + j;
                float s = (float)S[((size_t)(b * NP) + p) * NH + hrow + hh];
                float e = __expf(s - cs.x) * cs.y;
                w[j] = hmask[b * NP + p] ? (f16)e : (f16)0.0f;
            }
            *(f16x8*)&As[swz_idx(hh, g)] = w;
        }
#pragma unroll
        for (int i = 0; i < 4; ++i) {
            int slot = tid + 512 * i;
            int d = slot & 255;
            int g = slot >> 8;
            f16x8 w;
#pragma unroll
            for (int j = 0; j < 8; ++j)
                w[j] = (f16)P[(size_t)(k0 + g * 8 + j) * SD + b * ND + d0 + d];
            *(f16x8*)&Bs[swz_idx(d, g)] = w;
        }
        __syncthreads();
#pragma unroll
        for (int ks = 0; ks < 2; ++ks) {
            f16x8 a[4], bb[4];
#pragma unroll
            for (int m = 0; m < 4; ++m)
                a[m] = *(const f16x8*)&As[swz_idx(wr * 64 + m * 16 + l15, ks * 4 + lhi)];
#pragma unroll
            for (int n = 0; n < 4; ++n)
                bb[n] = *(const f16x8*)&Bs[swz_idx(wc * 64 + n * 16 + l15, ks * 4 + lhi)];
#pragma unroll
            for (int m = 0; m < 4; ++m)
#pragma unroll
                for (int n = 0; n < 4; ++n)
                    acc[m][n] = __builtin_amdgcn_mfma_f32_16x16x32_f16(a[m], bb[n], acc[m][n], 0, 0, 0);
        }
    }
#pragma unroll
    for (int m = 0; m < 4; ++m)
#pragma unroll
        for (int n = 0; n < 4; ++n) {
            int col = d0 + wc * 64 + n * 16 + l15;
#pragma unroll
            for (int r = 0; r < 4; ++r) {
                int row = hrow + wr * 64 + m * 16 + lhi * 4 + r;
                out2[((size_t)(b * NH) + row) * ND + col] = acc[m][n][r];
            }
        }
}

template<typename ST>
static void launch_legacy(const float* premises, const int* premises_mask,
                          const float* hypotheses, const int* hypotheses_mask,
                          float* out, float* out2, char* wsc, hipStream_t stream) {
    const size_t s_bytes = (size_t)NBATCH * NP * NH * sizeof(ST);
    ST*     S      = (ST*)wsc;
    float2* rstats = (float2*)(wsc + s_bytes);
    float2* cstats = (float2*)(wsc + s_bytes + 524288);
    float2* cpart  = (float2*)(wsc + s_bytes + 524288 + 262144);

    k1_scores<ST>  <<<dim3(4, 16, NBATCH), 512, 0, stream>>>(premises, hypotheses, S);
    k2_rowstats<ST><<<dim3(16384), 256, 0, stream>>>(S, premises_mask, rstats);
    k3a_colpart<ST><<<dim3(4, 8, NBATCH), 256, 0, stream>>>(S, hypotheses_mask, cpart);
    k3b_colmerge   <<<dim3(128), 256, 0, stream>>>(cpart, cstats);
    k4_newp<ST>    <<<dim3(2, 16, NBATCH), 512, 0, stream>>>(S, hypotheses, premises_mask, rstats, out);
    k5_newh<ST>    <<<dim3(2, 8, NBATCH), 512, 0, stream>>>(S, premises, hypotheses_mask, cstats, out2);
}

extern "C" void kernel_launch(void* const* d_in, const int* in_sizes, int n_in,
                              void* d_out, int out_size, void* d_ws, size_t ws_size,
                              hipStream_t stream) {
    const float* premises        = (const float*)d_in[0];
    const int*   premises_mask   = (const int*)d_in[1];
    const float* hypotheses      = (const float*)d_in[2];
    const int*   hypotheses_mask = (const int*)d_in[3];

    float* out  = (float*)d_out;
    float* out2 = out + (size_t)NBATCH * NP * ND;
    char*  wsc  = (char*)d_ws;

    const size_t S_BYTES  = (size_t)NBATCH * NP * NH * 4;   // 268,435,456
    const size_t STATS    = 524288 + 262144 + 2097152;      //   2,883,584
    const size_t PT_BYTES = (size_t)NBATCH * ND * NP * 2;   //  67,108,864
    const size_t HT_BYTES = (size_t)NBATCH * ND * NH * 2;   //  33,554,432
    const size_t need_v2  = S_BYTES + STATS + PT_BYTES + HT_BYTES; // ~372 MB
    const size_t need_f32 = S_BYTES + 4 * 1024 * 1024;

    if (ws_size >= need_v2) {
        float*  S      = (float*)wsc;
        float2* rstats = (float2*)(wsc + S_BYTES);
        float2* cstats = (float2*)(wsc + S_BYTES + 524288);
        float2* cpart  = (float2*)(wsc + S_BYTES + 524288 + 262144);
        f16*    Pt     = (f16*)(wsc + S_BYTES + STATS);
        f16*    Ht     = (f16*)(wsc + S_BYTES + STATS + PT_BYTES);

        tr_f16<NP>        <<<dim3(NP / 64, ND / 64, NBATCH), 256, 0, stream>>>(premises, Pt);
        tr_f16<NH>        <<<dim3(NH / 64, ND / 64, NBATCH), 256, 0, stream>>>(hypotheses, Ht);
        k1_scores<float>  <<<dim3(4, 16, NBATCH), 512, 0, stream>>>(premises, hypotheses, S);
        k2_rowstats<float><<<dim3(16384), 256, 0, stream>>>(S, premises_mask, rstats);
        k3a_colpart<float><<<dim3(4, 8, NBATCH), 256, 0, stream>>>(S, hypotheses_mask, cpart);
        k3b_colmerge      <<<dim3(128), 256, 0, stream>>>(cpart, cstats);
        k4_v2             <<<dim3(1, NP / 64, NBATCH), 512, 0, stream>>>(S, Ht, premises_mask, rstats, out);
        k5_v2             <<<dim3(1, NH / 64, NBATCH), 512, 0, stream>>>(S, Pt, hypotheses_mask, cstats, out2);
    } else if (ws_size >= need_f32) {
        launch_legacy<float>(premises, premises_mask, hypotheses, hypotheses_mask, out, out2, wsc, stream);
    } else {
        launch_legacy<f16>(premises, premises_mask, hypotheses, hypotheses_mask, out, out2, wsc, stream);
    }
}

// Round 10
// 1028.510 us; speedup vs baseline: 1.2841x; 1.0750x over previous
//
#include <hip/hip_runtime.h>
#include <cstdint>
#include <math.h>

#define NP 2048
#define NH 1024
#define NBATCH 32
#define ND 512
#define SD (NBATCH*ND)   // 16384: seq-row stride (floats) of premises/hypotheses [L,B,D]

typedef _Float16 f16;
typedef __attribute__((ext_vector_type(4))) _Float16 f16x4;
typedef __attribute__((ext_vector_type(8))) _Float16 f16x8;
typedef __attribute__((ext_vector_type(4))) float f32x4;

// LDS tile layout: [row][64 halves], 8-half groups XOR-swizzled by row&7.
__device__ __forceinline__ int swz_idx(int row, int g) {
    return (row << 6) + ((g ^ (row & 7)) << 3);
}

__device__ __forceinline__ void load8f(const f16* p, float* o) {
    f16x8 v = *(const f16x8*)p;
#pragma unroll
    for (int j = 0; j < 8; ++j) o[j] = (float)v[j];
}
__device__ __forceinline__ void load8f(const float* p, float* o) {
    float4 a = *(const float4*)p;
    float4 b = *(const float4*)(p + 4);
    o[0]=a.x; o[1]=a.y; o[2]=a.z; o[3]=a.w; o[4]=b.x; o[5]=b.y; o[6]=b.z; o[7]=b.w;
}

// ---------------- T0: transpose [L,B,D] fp32 -> [B][D][L] f16 ------------------------
template<int L>
__global__ __launch_bounds__(256) void tr_f16(const float* __restrict__ src,
                                              f16* __restrict__ dst) {
    __shared__ f16 t[64][68];               // +4 pad: write/read ~2-way max
    const int b  = blockIdx.z;
    const int l0 = blockIdx.x * 64;
    const int d0 = blockIdx.y * 64;
    const int r  = threadIdx.x >> 4;        // 0..15
    const int c  = threadIdx.x & 15;        // 0..15
#pragma unroll
    for (int i = 0; i < 4; ++i) {
        int l = r + 16 * i;
        float4 v = *(const float4*)(src + (size_t)(l0 + l) * SD + b * ND + d0 + c * 4);
        f16x4 h = {(f16)v.x, (f16)v.y, (f16)v.z, (f16)v.w};
        *(f16x4*)&t[l][c * 4] = h;          // 8B-aligned (row stride 136B = 17*8)
    }
    __syncthreads();
#pragma unroll
    for (int i = 0; i < 4; ++i) {
        int d = r + 16 * i;
        f16x4 h;
#pragma unroll
        for (int j = 0; j < 4; ++j) h[j] = t[c * 4 + j][d];
        *(f16x4*)(dst + ((size_t)b * ND + d0 + d) * L + l0 + c * 4) = h;
    }
}

// ---------------- K1: scores = P·H^T, issue-early/write-late pipelined ---------------
// Per K-step: barrier -> write prefetched regs to LDS -> barrier -> issue loads(kt+1)
// -> MFMA(kt). Loads stay in flight across the MFMA phase (T14).
template<typename ST>
__global__ __launch_bounds__(512) void k1_scores(const float* __restrict__ P,
                                                 const float* __restrict__ H,
                                                 ST* __restrict__ S) {
    __shared__ f16 As[128 * 64];   // [p-row][d-k]
    __shared__ f16 Bs[256 * 64];   // [h-row][d-k]
    const int b    = blockIdx.z;
    const int prow = blockIdx.y * 128;
    const int hcol = blockIdx.x * 256;
    const int tid  = threadIdx.x;
    const int lane = tid & 63, wid = tid >> 6;
    const int wr = wid >> 2, wc = wid & 3;     // 2 x 4 waves, wave tile 64x64
    const int l15 = lane & 15, lhi = lane >> 4;

    f32x4 acc[4][4] = {};
    float4 pa[4], pb[8];

    auto loadA = [&](int k0) {
#pragma unroll
        for (int i = 0; i < 4; ++i) {
            int s4 = tid + 512 * i;
            int row = s4 >> 4, c4 = (s4 & 15) << 2;
            pa[i] = *(const float4*)(P + (size_t)(prow + row) * SD + b * ND + k0 + c4);
        }
    };
    auto loadB = [&](int k0) {
#pragma unroll
        for (int i = 0; i < 8; ++i) {
            int s4 = tid + 512 * i;
            int row = s4 >> 4, c4 = (s4 & 15) << 2;
            pb[i] = *(const float4*)(H + (size_t)(hcol + row) * SD + b * ND + k0 + c4);
        }
    };

    loadA(0); loadB(0);                        // prologue: tile 0 -> regs

    for (int kt = 0; kt < 8; ++kt) {
        __syncthreads();                       // readers of tile kt-1 done
#pragma unroll
        for (int i = 0; i < 4; ++i) {          // write A tile kt
            int s4 = tid + 512 * i;
            int row = s4 >> 4, c4 = (s4 & 15) << 2;
            float4 v = pa[i];
            f16x4 h4 = {(f16)v.x, (f16)v.y, (f16)v.z, (f16)v.w};
            *(f16x4*)&As[swz_idx(row, c4 >> 3) + (c4 & 7)] = h4;
        }
#pragma unroll
        for (int i = 0; i < 8; ++i) {          // write B tile kt
            int s4 = tid + 512 * i;
            int row = s4 >> 4, c4 = (s4 & 15) << 2;
            float4 v = pb[i];
            f16x4 h4 = {(f16)v.x, (f16)v.y, (f16)v.z, (f16)v.w};
            *(f16x4*)&Bs[swz_idx(row, c4 >> 3) + (c4 & 7)] = h4;
        }
        __syncthreads();                       // tile kt visible
        const int kn = (kt < 7 ? kt + 1 : 7) * 64;
        loadA(kn); loadB(kn);                  // issue next-tile loads (in flight under MFMA)
#pragma unroll
        for (int ks = 0; ks < 2; ++ks) {
            f16x8 a[4], bb[4];
#pragma unroll
            for (int m = 0; m < 4; ++m)
                a[m] = *(const f16x8*)&As[swz_idx(wr * 64 + m * 16 + l15, ks * 4 + lhi)];
#pragma unroll
            for (int n = 0; n < 4; ++n)
                bb[n] = *(const f16x8*)&Bs[swz_idx(wc * 64 + n * 16 + l15, ks * 4 + lhi)];
#pragma unroll
            for (int m = 0; m < 4; ++m)
#pragma unroll
                for (int n = 0; n < 4; ++n)
                    acc[m][n] = __builtin_amdgcn_mfma_f32_16x16x32_f16(a[m], bb[n], acc[m][n], 0, 0, 0);
        }
    }
    const size_t sb = (size_t)b * NP * NH;
#pragma unroll
    for (int m = 0; m < 4; ++m)
#pragma unroll
        for (int n = 0; n < 4; ++n) {
            int col = hcol + wc * 64 + n * 16 + l15;
#pragma unroll
            for (int r = 0; r < 4; ++r) {
                int row = prow + wr * 64 + m * 16 + lhi * 4 + r;
                S[sb + (size_t)row * NH + col] = (ST)acc[m][n][r];
            }
        }
}

// ---------------- K2: per (b,p) row masked max / inv-sum over Nh ---------------------
template<typename ST>
__global__ __launch_bounds__(256) void k2_rowstats(const ST* __restrict__ S,
                                                   const int* __restrict__ pmask,
                                                   float2* __restrict__ rstats) {
    const int rowid = blockIdx.x * 4 + (threadIdx.x >> 6);   // b*2048+p
    const int lane  = threadIdx.x & 63;
    const int b     = rowid >> 11;
    const ST* row   = S + (size_t)rowid * NH + lane * 16;
    float s[16];
    load8f(row, s);
    load8f(row + 8, s + 8);
    int mk[16];
    {
        const int* mp = pmask + b * NH + lane * 16;
#pragma unroll
        for (int j = 0; j < 16; ++j) mk[j] = mp[j];
    }
    float m = -INFINITY;
#pragma unroll
    for (int j = 0; j < 16; ++j) if (mk[j]) m = fmaxf(m, s[j]);
#pragma unroll
    for (int off = 32; off; off >>= 1) m = fmaxf(m, __shfl_xor(m, off));
    float sum = 0.0f;
#pragma unroll
    for (int j = 0; j < 16; ++j) if (mk[j]) sum += __expf(s[j] - m);
#pragma unroll
    for (int off = 32; off; off >>= 1) sum += __shfl_xor(sum, off);
    if (lane == 0) rstats[rowid] = make_float2(m, sum > 0.0f ? 1.0f / sum : 0.0f);
}

// ---------------- K3a: per (b,h) partial masked online max/sum over a p-chunk --------
template<typename ST>
__global__ __launch_bounds__(256) void k3a_colpart(const ST* __restrict__ S,
                                                   const int* __restrict__ hmask,
                                                   float2* __restrict__ cpart) {
    const int b  = blockIdx.z;
    const int h  = blockIdx.x * 256 + threadIdx.x;
    const int pc = blockIdx.y;
    const ST* base = S + (size_t)b * NP * NH + h;
    const int* hm  = hmask + b * NP;
    float m = -INFINITY, sum = 0.0f;
    const int p0 = pc * 256;
    for (int p = p0; p < p0 + 256; ++p) {
        float s = (float)base[(size_t)p * NH];
        if (hm[p]) {
            if (s <= m) sum += __expf(s - m);
            else { sum = sum * __expf(m - s) + 1.0f; m = s; }
        }
    }
    cpart[((size_t)pc * NBATCH + b) * NH + h] = make_float2(m, sum);
}

// ---------------- K3b: merge 8 partials -> cstats ------------------------------------
__global__ __launch_bounds__(256) void k3b_colmerge(const float2* __restrict__ cpart,
                                                    float2* __restrict__ cstats) {
    const int cid = blockIdx.x * 256 + threadIdx.x;  // b*NH + h
    float2 v[8];
    float M = -INFINITY;
#pragma unroll
    for (int pc = 0; pc < 8; ++pc) {
        v[pc] = cpart[(size_t)pc * (NBATCH * NH) + cid];
        M = fmaxf(M, v[pc].x);
    }
    float Ssum = 0.0f;
#pragma unroll
    for (int pc = 0; pc < 8; ++pc)
        if (v[pc].y > 0.0f) Ssum += v[pc].y * __expf(v[pc].x - M);
    cstats[cid] = make_float2(M, Ssum > 0.0f ? 1.0f / Ssum : 0.0f);
}

// ---------------- K4 v2: new_premises = softmax_rows(S) @ H, pipelined ---------------
__global__ __launch_bounds__(512) void k4_v2(const float* __restrict__ S,
                                             const f16* __restrict__ Ht,
                                             const int* __restrict__ pmask,
                                             const float2* __restrict__ rstats,
                                             float* __restrict__ out) {
    __shared__ f16 As[64 * 64];    // [p][h-k]  softmax weights
    __shared__ f16 Bs[512 * 64];   // [d][h-k]  from Ht (already transposed)
    __shared__ float rm[64], ri[64];
    const int b    = blockIdx.z;
    const int prow = blockIdx.y * 64;
    const int tid  = threadIdx.x;
    const int lane = tid & 63, wid = tid >> 6;
    const int l15 = lane & 15, lhi = lane >> 4;

    if (tid < 64) {
        float2 v = rstats[b * NP + prow + tid];
        rm[tid] = v.x; ri[tid] = v.y;
    }
    const int arow = tid >> 3;          // 0..63
    const int ac8  = (tid & 7) << 3;    // 0..56

    f32x4 acc[4][4] = {};
    float4 psa[2];                      // S row chunk (8 f32)
    int4   pim[2];                      // pmask chunk (8 i32)
    f16x8  pbt[8];                      // Ht chunk

    auto loadA = [&](int k0) {
        const float* sp = S + ((size_t)(b * NP) + prow + arow) * NH + k0 + ac8;
        psa[0] = *(const float4*)sp;
        psa[1] = *(const float4*)(sp + 4);
        const int* mp = pmask + b * NH + k0 + ac8;
        pim[0] = *(const int4*)mp;
        pim[1] = *(const int4*)(mp + 4);
    };
    auto loadB = [&](int k0) {
#pragma unroll
        for (int i = 0; i < 8; ++i) {
            int slot = tid + 512 * i;
            int d = slot >> 3, g = slot & 7;
            pbt[i] = *(const f16x8*)(Ht + ((size_t)b * ND + d) * NH + k0 + g * 8);
        }
    };

    loadA(0); loadB(0);

    for (int kt = 0; kt < 16; ++kt) {
        __syncthreads();                       // readers done (also covers rm/ri init)
        {
            float sv[8] = {psa[0].x, psa[0].y, psa[0].z, psa[0].w,
                           psa[1].x, psa[1].y, psa[1].z, psa[1].w};
            int   mk[8] = {pim[0].x, pim[0].y, pim[0].z, pim[0].w,
                           pim[1].x, pim[1].y, pim[1].z, pim[1].w};
            float mrow = rm[arow], irow = ri[arow];
            f16x8 w;
#pragma unroll
            for (int j = 0; j < 8; ++j) {
                float e = __expf(sv[j] - mrow) * irow;
                w[j] = mk[j] ? (f16)e : (f16)0.0f;
            }
            *(f16x8*)&As[swz_idx(arow, ac8 >> 3)] = w;
        }
#pragma unroll
        for (int i = 0; i < 8; ++i) {
            int slot = tid + 512 * i;
            int d = slot >> 3, g = slot & 7;
            *(f16x8*)&Bs[swz_idx(d, g)] = pbt[i];
        }
        __syncthreads();
        const int kn = (kt < 15 ? kt + 1 : 15) * 64;
        loadA(kn); loadB(kn);                  // in flight under MFMA
#pragma unroll
        for (int ks = 0; ks < 2; ++ks) {
            f16x8 a[4], bb[4];
#pragma unroll
            for (int m = 0; m < 4; ++m)
                a[m] = *(const f16x8*)&As[swz_idx(m * 16 + l15, ks * 4 + lhi)];
#pragma unroll
            for (int n = 0; n < 4; ++n)
                bb[n] = *(const f16x8*)&Bs[swz_idx(wid * 64 + n * 16 + l15, ks * 4 + lhi)];
#pragma unroll
            for (int m = 0; m < 4; ++m)
#pragma unroll
                for (int n = 0; n < 4; ++n)
                    acc[m][n] = __builtin_amdgcn_mfma_f32_16x16x32_f16(a[m], bb[n], acc[m][n], 0, 0, 0);
        }
    }
#pragma unroll
    for (int m = 0; m < 4; ++m)
#pragma unroll
        for (int n = 0; n < 4; ++n) {
            int col = wid * 64 + n * 16 + l15;
#pragma unroll
            for (int r = 0; r < 4; ++r) {
                int row = prow + m * 16 + lhi * 4 + r;
                out[((size_t)(b * NP) + row) * ND + col] = acc[m][n][r];
            }
        }
}

// ---------------- K5 v2: new_hypotheses = softmax_cols(S)^T @ P, pipelined -----------
__global__ __launch_bounds__(512) void k5_v2(const float* __restrict__ S,
                                             const f16* __restrict__ Pt,
                                             const int* __restrict__ hmask,
                                             const float2* __restrict__ cstats,
                                             float* __restrict__ out2) {
    __shared__ f16 As[64 * 64];    // [h][p-k]  weights (from S transposed read)
    __shared__ f16 Bs[512 * 64];   // [d][p-k]  from Pt (already transposed)
    const int b    = blockIdx.z;
    const int hrow = blockIdx.y * 64;
    const int tid  = threadIdx.x;
    const int lane = tid & 63, wid = tid >> 6;
    const int l15 = lane & 15, lhi = lane >> 4;

    const int hh = lane;                                  // A-stage row
    const float2 cs = cstats[b * NH + hrow + hh];         // hoisted out of K-loop
    const int* hm = hmask + b * NP;

    f32x4 acc[4][4] = {};
    float  pss[8];                     // S column chunk (8 p, strided)
    int4   pim[2];                     // hmask chunk (8 p, wave-uniform)
    f16x8  pbt[8];                     // Pt chunk

    auto loadA = [&](int k0) {
#pragma unroll
        for (int j = 0; j < 8; ++j) {
            int p = k0 + wid * 8 + j;
            pss[j] = S[((size_t)(b * NP) + p) * NH + hrow + hh];
        }
        pim[0] = *(const int4*)(hm + k0 + wid * 8);
        pim[1] = *(const int4*)(hm + k0 + wid * 8 + 4);
    };
    auto loadB = [&](int k0) {
#pragma unroll
        for (int i = 0; i < 8; ++i) {
            int slot = tid + 512 * i;
            int d = slot >> 3, g = slot & 7;
            pbt[i] = *(const f16x8*)(Pt + ((size_t)b * ND + d) * NP + k0 + g * 8);
        }
    };

    loadA(0); loadB(0);

    for (int kt = 0; kt < 32; ++kt) {
        __syncthreads();
        {
            int mk[8] = {pim[0].x, pim[0].y, pim[0].z, pim[0].w,
                         pim[1].x, pim[1].y, pim[1].z, pim[1].w};
            f16x8 w;
#pragma unroll
            for (int j = 0; j < 8; ++j) {
                float e = __expf(pss[j] - cs.x) * cs.y;
                w[j] = mk[j] ? (f16)e : (f16)0.0f;
            }
            *(f16x8*)&As[swz_idx(hh, wid)] = w;
        }
#pragma unroll
        for (int i = 0; i < 8; ++i) {
            int slot = tid + 512 * i;
            int d = slot >> 3, g = slot & 7;
            *(f16x8*)&Bs[swz_idx(d, g)] = pbt[i];
        }
        __syncthreads();
        const int kn = (kt < 31 ? kt + 1 : 31) * 64;
        loadA(kn); loadB(kn);              // in flight under MFMA
#pragma unroll
        for (int ks = 0; ks < 2; ++ks) {
            f16x8 a[4], bb[4];
#pragma unroll
            for (int m = 0; m < 4; ++m)
                a[m] = *(const f16x8*)&As[swz_idx(m * 16 + l15, ks * 4 + lhi)];
#pragma unroll
            for (int n = 0; n < 4; ++n)
                bb[n] = *(const f16x8*)&Bs[swz_idx(wid * 64 + n * 16 + l15, ks * 4 + lhi)];
#pragma unroll
            for (int m = 0; m < 4; ++m)
#pragma unroll
                for (int n = 0; n < 4; ++n)
                    acc[m][n] = __builtin_amdgcn_mfma_f32_16x16x32_f16(a[m], bb[n], acc[m][n], 0, 0, 0);
        }
    }
#pragma unroll
    for (int m = 0; m < 4; ++m)
#pragma unroll
        for (int n = 0; n < 4; ++n) {
            int col = wid * 64 + n * 16 + l15;
#pragma unroll
            for (int r = 0; r < 4; ++r) {
                int row = hrow + m * 16 + lhi * 4 + r;
                out2[((size_t)(b * NH) + row) * ND + col] = acc[m][n][r];
            }
        }
}

// ---------------- legacy K4/K5 (fallback tiers, unchanged) ---------------------------
template<typename ST>
__global__ __launch_bounds__(512) void k4_newp(const ST* __restrict__ S,
                                               const float* __restrict__ H,
                                               const int* __restrict__ pmask,
                                               const float2* __restrict__ rstats,
                                               float* __restrict__ out) {
    __shared__ f16 As[128 * 64];
    __shared__ f16 Bs[256 * 64];
    __shared__ float rm[128], ri[128];
    const int b    = blockIdx.z;
    const int prow = blockIdx.y * 128;
    const int d0   = blockIdx.x * 256;
    const int tid  = threadIdx.x;
    const int lane = tid & 63, wid = tid >> 6;
    const int wr = wid >> 2, wc = wid & 3;
    const int l15 = lane & 15, lhi = lane >> 4;

    if (tid < 128) {
        float2 v = rstats[b * NP + prow + tid];
        rm[tid] = v.x; ri[tid] = v.y;
    }
    f32x4 acc[4][4] = {};
    for (int kt = 0; kt < 16; ++kt) {
        const int k0 = kt * 64;
        __syncthreads();
#pragma unroll
        for (int i = 0; i < 2; ++i) {
            int s8 = tid + 512 * i;
            int row = s8 >> 3;
            int c8 = (s8 & 7) << 3;
            float sv[8];
            load8f(S + ((size_t)(b * NP) + prow + row) * NH + k0 + c8, sv);
            const int* pm = pmask + b * NH + k0 + c8;
            float mrow = rm[row], irow = ri[row];
            f16x8 w;
#pragma unroll
            for (int j = 0; j < 8; ++j) {
                float e = __expf(sv[j] - mrow) * irow;
                w[j] = pm[j] ? (f16)e : (f16)0.0f;
            }
            *(f16x8*)&As[swz_idx(row, c8 >> 3)] = w;
        }
#pragma unroll
        for (int i = 0; i < 4; ++i) {
            int slot = tid + 512 * i;
            int d = slot & 255;
            int g = slot >> 8;
            f16x8 w;
#pragma unroll
            for (int j = 0; j < 8; ++j)
                w[j] = (f16)H[(size_t)(k0 + g * 8 + j) * SD + b * ND + d0 + d];
            *(f16x8*)&Bs[swz_idx(d, g)] = w;
        }
        __syncthreads();
#pragma unroll
        for (int ks = 0; ks < 2; ++ks) {
            f16x8 a[4], bb[4];
#pragma unroll
            for (int m = 0; m < 4; ++m)
                a[m] = *(const f16x8*)&As[swz_idx(wr * 64 + m * 16 + l15, ks * 4 + lhi)];
#pragma unroll
            for (int n = 0; n < 4; ++n)
                bb[n] = *(const f16x8*)&Bs[swz_idx(wc * 64 + n * 16 + l15, ks * 4 + lhi)];
#pragma unroll
            for (int m = 0; m < 4; ++m)
#pragma unroll
                for (int n = 0; n < 4; ++n)
                    acc[m][n] = __builtin_amdgcn_mfma_f32_16x16x32_f16(a[m], bb[n], acc[m][n], 0, 0, 0);
        }
    }
#pragma unroll
    for (int m = 0; m < 4; ++m)
#pragma unroll
        for (int n = 0; n < 4; ++n) {
            int col = d0 + wc * 64 + n * 16 + l15;
#pragma unroll
            for (int r = 0; r < 4; ++r) {
                int row = prow + wr * 64 + m * 16 + lhi * 4 + r;
                out[((size_t)(b * NP) + row) * ND + col] = acc[m][n][r];
            }
        }
}

template<typename ST>
__global__ __launch_bounds__(512) void k5_newh(const ST* __restrict__ S,
                                               const float* __restrict__ P,
                                               const int* __restrict__ hmask,
                                               const float2* __restrict__ cstats,
                                               float* __restrict__ out2) {
    __shared__ f16 As[128 * 64];
    __shared__ f16 Bs[256 * 64];
    const int b    = blockIdx.z;
    const int hrow = blockIdx.y * 128;
    const int d0   = blockIdx.x * 256;
    const int tid  = threadIdx.x;
    const int lane = tid & 63, wid = tid >> 6;
    const int wr = wid >> 2, wc = wid & 3;
    const int l15 = lane & 15, lhi = lane >> 4;

    f32x4 acc[4][4] = {};
    for (int kt = 0; kt < 32; ++kt) {
        const int k0 = kt * 64;
        __syncthreads();
#pragma unroll
        for (int i = 0; i < 2; ++i) {
            int slot = tid + 512 * i;
            int hh = slot & 127;
            int g = slot >> 7;
            float2 cs = cstats[b * NH + hrow + hh];
            f16x8 w;
#pragma unroll
            for (int j = 0; j < 8; ++j) {
                int p = k0 + g * 8 + j;
                float s = (float)S[((size_t)(b * NP) + p) * NH + hrow + hh];
                float e = __expf(s - cs.x) * cs.y;
                w[j] = hmask[b * NP + p] ? (f16)e : (f16)0.0f;
            }
            *(f16x8*)&As[swz_idx(hh, g)] = w;
        }
#pragma unroll
        for (int i = 0; i < 4; ++i) {
            int slot = tid + 512 * i;
            int d = slot & 255;
            int g = slot >> 8;
            f16x8 w;
#pragma unroll
            for (int j = 0; j < 8; ++j)
                w[j] = (f16)P[(size_t)(k0 + g * 8 + j) * SD + b * ND + d0 + d];
            *(f16x8*)&Bs[swz_idx(d, g)] = w;
        }
        __syncthreads();
#pragma unroll
        for (int ks = 0; ks < 2; ++ks) {
            f16x8 a[4], bb[4];
#pragma unroll
            for (int m = 0; m < 4; ++m)
                a[m] = *(const f16x8*)&As[swz_idx(wr * 64 + m * 16 + l15, ks * 4 + lhi)];
#pragma unroll
            for (int n = 0; n < 4; ++n)
                bb[n] = *(const f16x8*)&Bs[swz_idx(wc * 64 + n * 16 + l15, ks * 4 + lhi)];
#pragma unroll
            for (int m = 0; m < 4; ++m)
#pragma unroll
                for (int n = 0; n < 4; ++n)
                    acc[m][n] = __builtin_amdgcn_mfma_f32_16x16x32_f16(a[m], bb[n], acc[m][n], 0, 0, 0);
        }
    }
#pragma unroll
    for (int m = 0; m < 4; ++m)
#pragma unroll
        for (int n = 0; n < 4; ++n) {
            int col = d0 + wc * 64 + n * 16 + l15;
#pragma unroll
            for (int r = 0; r < 4; ++r) {
                int row = hrow + wr * 64 + m * 16 + lhi * 4 + r;
                out2[((size_t)(b * NH) + row) * ND + col] = acc[m][n][r];
            }
        }
}

template<typename ST>
static void launch_legacy(const float* premises, const int* premises_mask,
                          const float* hypotheses, const int* hypotheses_mask,
                          float* out, float* out2, char* wsc, hipStream_t stream) {
    const size_t s_bytes = (size_t)NBATCH * NP * NH * sizeof(ST);
    ST*     S      = (ST*)wsc;
    float2* rstats = (float2*)(wsc + s_bytes);
    float2* cstats = (float2*)(wsc + s_bytes + 524288);
    float2* cpart  = (float2*)(wsc + s_bytes + 524288 + 262144);

    k1_scores<ST>  <<<dim3(4, 16, NBATCH), 512, 0, stream>>>(premises, hypotheses, S);
    k2_rowstats<ST><<<dim3(16384), 256, 0, stream>>>(S, premises_mask, rstats);
    k3a_colpart<ST><<<dim3(4, 8, NBATCH), 256, 0, stream>>>(S, hypotheses_mask, cpart);
    k3b_colmerge   <<<dim3(128), 256, 0, stream>>>(cpart, cstats);
    k4_newp<ST>    <<<dim3(2, 16, NBATCH), 512, 0, stream>>>(S, hypotheses, premises_mask, rstats, out);
    k5_newh<ST>    <<<dim3(2, 8, NBATCH), 512, 0, stream>>>(S, premises, hypotheses_mask, cstats, out2);
}

extern "C" void kernel_launch(void* const* d_in, const int* in_sizes, int n_in,
                              void* d_out, int out_size, void* d_ws, size_t ws_size,
                              hipStream_t stream) {
    const float* premises        = (const float*)d_in[0];
    const int*   premises_mask   = (const int*)d_in[1];
    const float* hypotheses      = (const float*)d_in[2];
    const int*   hypotheses_mask = (const int*)d_in[3];

    float* out  = (float*)d_out;
    float* out2 = out + (size_t)NBATCH * NP * ND;
    char*  wsc  = (char*)d_ws;

    const size_t S_BYTES  = (size_t)NBATCH * NP * NH * 4;   // 268,435,456
    const size_t STATS    = 524288 + 262144 + 2097152;      //   2,883,584
    const size_t PT_BYTES = (size_t)NBATCH * ND * NP * 2;   //  67,108,864
    const size_t HT_BYTES = (size_t)NBATCH * ND * NH * 2;   //  33,554,432
    const size_t need_v2  = S_BYTES + STATS + PT_BYTES + HT_BYTES; // ~372 MB
    const size_t need_f32 = S_BYTES + 4 * 1024 * 1024;

    if (ws_size >= need_v2) {
        float*  S      = (float*)wsc;
        float2* rstats = (float2*)(wsc + S_BYTES);
        float2* cstats = (float2*)(wsc + S_BYTES + 524288);
        float2* cpart  = (float2*)(wsc + S_BYTES + 524288 + 262144);
        f16*    Pt     = (f16*)(wsc + S_BYTES + STATS);
        f16*    Ht     = (f16*)(wsc + S_BYTES + STATS + PT_BYTES);

        tr_f16<NP>        <<<dim3(NP / 64, ND / 64, NBATCH), 256, 0, stream>>>(premises, Pt);
        tr_f16<NH>        <<<dim3(NH / 64, ND / 64, NBATCH), 256, 0, stream>>>(hypotheses, Ht);
        k1_scores<float>  <<<dim3(4, 16, NBATCH), 512, 0, stream>>>(premises, hypotheses, S);
        k2_rowstats<float><<<dim3(16384), 256, 0, stream>>>(S, premises_mask, rstats);
        k3a_colpart<float><<<dim3(4, 8, NBATCH), 256, 0, stream>>>(S, hypotheses_mask, cpart);
        k3b_colmerge      <<<dim3(128), 256, 0, stream>>>(cpart, cstats);
        k4_v2             <<<dim3(1, NP / 64, NBATCH), 512, 0, stream>>>(S, Ht, premises_mask, rstats, out);
        k5_v2             <<<dim3(1, NH / 64, NBATCH), 512, 0, stream>>>(S, Pt, hypotheses_mask, cstats, out2);
    } else if (ws_size >= need_f32) {
        launch_legacy<float>(premises, premises_mask, hypotheses, hypotheses_mask, out, out2, wsc, stream);
    } else {
        launch_legacy<f16>(premises, premises_mask, hypotheses, hypotheses_mask, out, out2, wsc, stream);
    }
}